// Round 9
// baseline (1140.665 us; speedup 1.0000x reference)
//
#include <hip/hip_runtime.h>
#include <hip/hip_bf16.h>

typedef __attribute__((ext_vector_type(8))) __bf16 bf16x8;
typedef __attribute__((ext_vector_type(4))) __bf16 bf16x4;
typedef __attribute__((ext_vector_type(4))) float f32x4;

#define MFMA16(a,b,c) __builtin_amdgcn_mfma_f32_16x16x32_bf16(a,b,c,0,0,0)

__device__ __forceinline__ void gload_lds16(const void* g, void* l) {
  __builtin_amdgcn_global_load_lds(
      (const __attribute__((address_space(1))) void*)g,
      (__attribute__((address_space(3))) void*)l, 16, 0, 0);
}

__device__ __forceinline__ f32x4 max4(f32x4 a, f32x4 b) {
  f32x4 c;
  c[0] = fmaxf(a[0], b[0]); c[1] = fmaxf(a[1], b[1]);
  c[2] = fmaxf(a[2], b[2]); c[3] = fmaxf(a[3], b[3]);
  return c;
}

// ---------------------------------------------------------------------------
// prep: cast weights to bf16, build padded bf16 bias table [16][64][64]
// ---------------------------------------------------------------------------
__global__ void prep_k(const float* __restrict__ qkv_w, const float* __restrict__ out_w,
                       const float* __restrict__ rpt,
                       __bf16* __restrict__ qwb, __bf16* __restrict__ owb,
                       __bf16* __restrict__ biasb)
{
  int i = blockIdx.x * 256 + threadIdx.x;
  if (i < 786432) { qwb[i] = (__bf16)qkv_w[i]; return; }
  i -= 786432;
  if (i < 262144) { owb[i] = (__bf16)out_w[i]; return; }
  i -= 262144;
  if (i < 65536) {
    int hh = i >> 12, qc = i & 4095, qq = qc >> 6, c = qc & 63;
    __bf16 val;
    if (c >= 49)      val = (__bf16)(-30000.0f);
    else if (qq >= 49) val = (__bf16)(0.0f);
    else {
      int dh = qq / 7 - c / 7 + 6;
      int dw = qq % 7 - c % 7 + 6;
      val = (__bf16)rpt[(dh * 13 + dw) * 16 + hh];
    }
    biasb[i] = val;
  }
}

// ---------------------------------------------------------------------------
// cast hidden_states f32 -> bf16 (8 elems/thread)
// ---------------------------------------------------------------------------
__global__ void cast_k(const float* __restrict__ in, __bf16* __restrict__ outb, int n8)
{
  int i = blockIdx.x * blockDim.x + threadIdx.x;
  int stride = gridDim.x * blockDim.x;
  for (; i < n8; i += stride) {
    const float4* p = (const float4*)in + (size_t)i * 2;
    float4 x = p[0], y = p[1];
    bf16x8 o;
    o[0] = (__bf16)x.x; o[1] = (__bf16)x.y; o[2] = (__bf16)x.z; o[3] = (__bf16)x.w;
    o[4] = (__bf16)y.x; o[5] = (__bf16)y.y; o[6] = (__bf16)y.z; o[7] = (__bf16)y.w;
    ((bf16x8*)outb)[i] = o;
  }
}

// ---------------------------------------------------------------------------
// B-stationary persistent GEMM.  C[m,n] = sum_k A[m,k]*Bt[n,k], K=512 fixed.
// Each block owns a 128-wide n-strip: B[128][512] bf16 = 128 KB staged into
// LDS ONCE (swizzled: chunk ^= n&7 -> 2-way-max bank aliasing, free), then
// loops over m-tiles of 256x128 (8 waves, 4m x 2n, 64x64 each).
// A is streamed global -> VGPR (16 full 64B lines per frag-load, L1 dedup
// across the wc-pair) with one-K-tile-ahead ping-pong prefetch.
// NO barriers and NO inline asm in the m-loop: all deps compiler-visible,
// 8 waves free-run (m114 overlap). Per-block fixed costs amortized over
// ~6 m-tiles. Swapped MFMA operands (round-7 verified): m -> r axis,
// n -> g*4+j axis -> wide stores (bf16x4 / f32x4).
// ---------------------------------------------------------------------------
template<int EPI>
__global__ __launch_bounds__(512, 1)
void gemmbs(const __bf16* __restrict__ A, const __bf16* __restrict__ Bt,
            const float* __restrict__ bvec, float* __restrict__ outp,
            __bf16* __restrict__ qb, __bf16* __restrict__ kb, __bf16* __restrict__ vb,
            int nstrips, int groups)
{
  __shared__ __align__(16) char ldsB[131072];
  const int tid = threadIdx.x;
  const int wave = tid >> 6, lane = tid & 63;
  const int g = lane >> 4, r = lane & 15;
  const int wr = wave >> 1, wc = wave & 1;        // 4 m-slots x 2 n-slots
  const int strip = blockIdx.x % nstrips;
  const int mg = blockIdx.x / nstrips;

  // ---- stage B-panel once (linear LDS dest, pre-swizzled global source)
  {
    const __bf16* Bg = Bt + (size_t)strip * 128 * 512;
#pragma unroll
    for (int i = 0; i < 16; ++i) {
      int n = i * 8 + wave;                        // n&7 == wave
      gload_lds16(Bg + (size_t)n * 512 + (lane ^ wave) * 8,
                  ldsB + i * 8192 + tid * 16);
    }
    asm volatile("s_waitcnt vmcnt(0)" ::: "memory");
    __syncthreads();                               // only barrier in kernel
  }

  // B-frag addressing (row nloc: 1024 B; logical chunk c read at c^(nloc&7))
  int bbase[4], bswz[4];
#pragma unroll
  for (int ni = 0; ni < 4; ++ni) {
    int nloc = wc * 64 + ni * 16 + r;
    bbase[ni] = nloc * 1024;
    bswz[ni] = nloc & 7;
  }

  // bias (n is 4-aligned via g*4)
  f32x4 bv4[4];
#pragma unroll
  for (int ni = 0; ni < 4; ++ni)
    bv4[ni] = *(const f32x4*)(bvec + strip * 128 + wc * 64 + ni * 16 + g * 4);

  // qkv scatter constants (EPI==0)
  __bf16* dst = qb; float scl = 0.17677669529663687f;
  int hh_[4], d0_[4];
  if (EPI == 0) {
    const int which = strip >> 2;                  // 4 strips per q/k/v
    if (which == 1)      { dst = kb; scl = 1.0f; }
    else if (which == 2) { dst = vb; scl = 1.0f; }
#pragma unroll
    for (int ni = 0; ni < 4; ++ni) {
      int nl = (strip * 128 + wc * 64 + ni * 16) & 511;
      hh_[ni] = nl >> 5;
      d0_[ni] = (nl & 31) + g * 4;
    }
  }

#define LOADA(S, KT) { _Pragma("unroll")                                       \
  for (int mi_ = 0; mi_ < 4; ++mi_) {                                          \
    S[mi_][0] = *(const bf16x8*)(ap + mi_ * 8192 + (KT) * 64);                 \
    S[mi_][1] = *(const bf16x8*)(ap + mi_ * 8192 + (KT) * 64 + 32); } }

#define DOKT(S, KT) { bf16x8 bf_[4][2];                                        \
  _Pragma("unroll")                                                            \
  for (int ni_ = 0; ni_ < 4; ++ni_) {                                          \
    bf_[ni_][0] = *(const bf16x8*)(ldsB + bbase[ni_] +                         \
                    ((((KT) * 8 + g) ^ bswz[ni_]) << 4));                      \
    bf_[ni_][1] = *(const bf16x8*)(ldsB + bbase[ni_] +                         \
                    ((((KT) * 8 + 4 + g) ^ bswz[ni_]) << 4)); }                \
  _Pragma("unroll")                                                            \
  for (int mi_ = 0; mi_ < 4; ++mi_)                                            \
    _Pragma("unroll")                                                          \
    for (int ni_ = 0; ni_ < 4; ++ni_) {                                        \
      acc[mi_][ni_] = MFMA16(bf_[ni_][0], S[mi_][0], acc[mi_][ni_]);           \
      acc[mi_][ni_] = MFMA16(bf_[ni_][1], S[mi_][1], acc[mi_][ni_]); } }

  // ---- m-loop: 392 m-tiles total, this block takes mg, mg+groups, ...
  for (int mt = mg; mt < 392; mt += groups) {
    const __bf16* ap = A + ((size_t)mt * 256 + wr * 64 + r) * 512 + g * 8;
    f32x4 acc[4][4] = {};
    bf16x8 aX[4][2], aY[4][2];

    LOADA(aX, 0)
#pragma unroll
    for (int kt = 0; kt < 8; ++kt) {
      if (kt < 7) { if (kt & 1) LOADA(aX, kt + 1) else LOADA(aY, kt + 1) }
      if (kt & 1) DOKT(aY, kt) else DOKT(aX, kt)
    }

    if (EPI == 1) {
#pragma unroll
      for (int mi = 0; mi < 4; ++mi) {
        int m = mt * 256 + wr * 64 + mi * 16 + r;
        float* orow = outp + (size_t)m * 512 + strip * 128 + wc * 64 + g * 4;
#pragma unroll
        for (int ni = 0; ni < 4; ++ni) {
          f32x4 w = acc[mi][ni] + bv4[ni];
          *(f32x4*)(orow + ni * 16) = w;
        }
      }
    } else {
#pragma unroll
      for (int mi = 0; mi < 4; ++mi) {
        int m = mt * 256 + wr * 64 + mi * 16 + r;
        int bb = m / 49, t49 = m - bb * 49;
        __bf16* dr = dst + (size_t)bb * 25088 + t49 * 32;
#pragma unroll
        for (int ni = 0; ni < 4; ++ni) {
          f32x4 v = acc[mi][ni];
          bf16x4 w;
#pragma unroll
          for (int j = 0; j < 4; ++j) w[j] = (__bf16)((v[j] + bv4[ni][j]) * scl);
          *(bf16x4*)(dr + hh_[ni] * 1568 + d0_[ni]) = w;
        }
      }
    }
  }
#undef LOADA
#undef DOKT
}

// ---------------------------------------------------------------------------
// Attention: 4 waves/block = 4 heads of one b (unchanged from round 2).
// ---------------------------------------------------------------------------
__global__ __launch_bounds__(256, 4)
void attn_k(const __bf16* __restrict__ qb, const __bf16* __restrict__ kb,
            const __bf16* __restrict__ vb, const __bf16* __restrict__ bias_p,
            const float* __restrict__ mask, __bf16* __restrict__ ao)
{
  __shared__ float maskl[64 * 64];
  __shared__ __bf16 Vt[4][32 * 64];
  __shared__ __bf16 Pl[4][16 * 64];
  const int tid = threadIdx.x, wave = tid >> 6, lane = tid & 63;
  const int g = lane >> 4, r = lane & 15;
  const int b = blockIdx.x >> 2, hg = blockIdx.x & 3;
  const int h = hg * 4 + wave;
  const size_t bh = (size_t)b * 16 + h;
  const __bf16* q = qb + bh * 1568;
  const __bf16* k = kb + bh * 1568;
  const __bf16* v = vb + bh * 1568;
  const bf16x8 z8 = {};
  const f32x4 z4 = {};

  bf16x8* vtz = (bf16x8*)Vt[wave];
#pragma unroll
  for (int i = 0; i < 4; ++i) vtz[i * 64 + lane] = z8;

  const float* mb = mask + (size_t)b * 2401;
#pragma unroll
  for (int i = 0; i < 16; ++i) {
    int idx = i * 256 + tid;
    int qq = idx >> 6, c = idx & 63;
    float mv = (qq < 49 && c < 49) ? mb[qq * 49 + c] : 0.0f;
    maskl[qq * 64 + (c ^ ((qq & 7) << 2))] = mv;
  }

  bf16x8 kf[4], qf[4];
#pragma unroll
  for (int i = 0; i < 4; ++i) {
    int row = i * 16 + r;
    kf[i] = (row < 49) ? *(const bf16x8*)(k + row * 32 + g * 8) : z8;
    qf[i] = (row < 49) ? *(const bf16x8*)(q + row * 32 + g * 8) : z8;
  }

  __syncthreads();

  char* vt = (char*)Vt[wave];
#pragma unroll
  for (int i = 0; i < 4; ++i) {
    int idx = i * 64 + lane;
    int t = idx >> 2, d0 = (idx & 3) << 3;
    if (t < 49) {
      bf16x8 vv = *(const bf16x8*)(v + t * 32 + d0);
#pragma unroll
      for (int j = 0; j < 8; ++j) {
        int d = d0 + j;
        *(__bf16*)(vt + d * 128 + ((t * 2) ^ ((d & 7) << 4))) = vv[j];
      }
    }
  }

  bf16x8 vf[2][2];
#pragma unroll
  for (int di = 0; di < 2; ++di) {
    int row = di * 16 + r;
#pragma unroll
    for (int t = 0; t < 2; ++t)
      vf[di][t] = *(const bf16x8*)(vt + row * 128 + (((t * 32 + g * 8) * 2) ^ ((row & 7) << 4)));
  }

  const __bf16* bp = bias_p + h * 4096;
  char* pw = (char*)Pl[wave];
  __bf16* aob = ao + (size_t)b * 25088 + h * 32;
  const int swz = (r & 7) << 4;
  const int mswz = (r & 7) << 2;

#pragma unroll
  for (int qi = 0; qi < 4; ++qi) {
    f32x4 s[4];
#pragma unroll
    for (int mi = 0; mi < 4; ++mi) s[mi] = MFMA16(kf[mi], qf[qi], z4);

    const int qrow = qi * 16 + r;
#pragma unroll
    for (int mi = 0; mi < 4; ++mi) {
      int c0 = mi * 16 + g * 4;
      bf16x4 b4 = *(const bf16x4*)(bp + qrow * 64 + c0);
      f32x4 m4 = *(const f32x4*)(maskl + qrow * 64 + (c0 ^ mswz));
#pragma unroll
      for (int jj = 0; jj < 4; ++jj)
        s[mi][jj] += (float)b4[jj] + m4[jj];
    }
    f32x4 aa = max4(max4(s[0], s[1]), max4(s[2], s[3]));
    float mx = fmaxf(fmaxf(aa[0], aa[1]), fmaxf(aa[2], aa[3]));
    mx = fmaxf(mx, __shfl_xor(mx, 16));
    mx = fmaxf(mx, __shfl_xor(mx, 32));
    float sum = 0.0f;
#pragma unroll
    for (int mi = 0; mi < 4; ++mi) {
#pragma unroll
      for (int jj = 0; jj < 4; ++jj) {
        float e = __expf(s[mi][jj] - mx);
        s[mi][jj] = e;
        sum += e;
      }
    }
    sum += __shfl_xor(sum, 16);
    sum += __shfl_xor(sum, 32);
    const float rinv = 1.0f / sum;

#pragma unroll
    for (int mi = 0; mi < 4; ++mi) {
      bf16x4 w;
#pragma unroll
      for (int jj = 0; jj < 4; ++jj) w[jj] = (__bf16)(s[mi][jj] * rinv);
      *(bf16x4*)(pw + r * 128 + (((mi * 16 + g * 4) * 2) ^ swz)) = w;
    }
    bf16x8 pa0 = *(const bf16x8*)(pw + r * 128 + ((g * 16) ^ swz));
    bf16x8 pa1 = *(const bf16x8*)(pw + r * 128 + ((64 + g * 16) ^ swz));

#pragma unroll
    for (int di = 0; di < 2; ++di) {
      f32x4 o = MFMA16(pa0, vf[di][0], z4);
      o = MFMA16(pa1, vf[di][1], o);
#pragma unroll
      for (int jj = 0; jj < 4; ++jj) {
        int qq = qi * 16 + g * 4 + jj;
        if (qq < 49)
          aob[(size_t)qq * 512 + di * 16 + r] = (__bf16)o[jj];
      }
    }
  }
}

// ---------------------------------------------------------------------------
extern "C" void kernel_launch(void* const* d_in, const int* in_sizes, int n_in,
                              void* d_out, int out_size, void* d_ws, size_t ws_size,
                              hipStream_t stream)
{
  const float* hs    = (const float*)d_in[0];
  const float* mask  = (const float*)d_in[1];
  const float* qkv_w = (const float*)d_in[2];
  const float* qkv_b = (const float*)d_in[3];
  const float* out_w = (const float*)d_in[4];
  const float* out_b = (const float*)d_in[5];
  const float* rpt   = (const float*)d_in[6];
  float* out = (float*)d_out;

  char* ws = (char*)d_ws;
  __bf16* hsb  = (__bf16*)(ws);                  // reused as attn-out after GEMM1
  __bf16* qb   = (__bf16*)(ws + 102760448);
  __bf16* kb   = (__bf16*)(ws + 205520896);
  __bf16* vb   = (__bf16*)(ws + 308281344);
  __bf16* qwb  = (__bf16*)(ws + 411041792);
  __bf16* owb  = (__bf16*)(ws + 412614656);
  __bf16* biasb= (__bf16*)(ws + 413138944);      // [16][64][64] bf16

  prep_k<<<4352, 256, 0, stream>>>(qkv_w, out_w, rpt, qwb, owb, biasb);
  cast_k<<<2048, 256, 0, stream>>>(hs, hsb, 6422528);
  gemmbs<0><<<768, 512, 0, stream>>>(hsb, qwb, qkv_b, nullptr, qb, kb, vb, 12, 64);
  attn_k<<<8192, 256, 0, stream>>>(qb, kb, vb, biasb, mask, hsb);
  gemmbs<1><<<256, 512, 0, stream>>>(hsb, owb, out_b, out, nullptr, nullptr, nullptr, 4, 64);
}

// Round 10
// 648.735 us; speedup vs baseline: 1.7583x; 1.7583x over previous
//
#include <hip/hip_runtime.h>
#include <hip/hip_bf16.h>

typedef __attribute__((ext_vector_type(8))) __bf16 bf16x8;
typedef __attribute__((ext_vector_type(4))) __bf16 bf16x4;
typedef __attribute__((ext_vector_type(4))) float f32x4;

#define MFMA16(a,b,c) __builtin_amdgcn_mfma_f32_16x16x32_bf16(a,b,c,0,0,0)

__device__ __forceinline__ void gload_lds16(const void* g, void* l) {
  __builtin_amdgcn_global_load_lds(
      (const __attribute__((address_space(1))) void*)g,
      (__attribute__((address_space(3))) void*)l, 16, 0, 0);
}

__device__ __forceinline__ f32x4 max4(f32x4 a, f32x4 b) {
  f32x4 c;
  c[0] = fmaxf(a[0], b[0]); c[1] = fmaxf(a[1], b[1]);
  c[2] = fmaxf(a[2], b[2]); c[3] = fmaxf(a[3], b[3]);
  return c;
}

// ---------------------------------------------------------------------------
// prep: cast weights to bf16, build padded bf16 bias table [16][64][64]
// ---------------------------------------------------------------------------
__global__ void prep_k(const float* __restrict__ qkv_w, const float* __restrict__ out_w,
                       const float* __restrict__ rpt,
                       __bf16* __restrict__ qwb, __bf16* __restrict__ owb,
                       __bf16* __restrict__ biasb)
{
  int i = blockIdx.x * 256 + threadIdx.x;
  if (i < 786432) { qwb[i] = (__bf16)qkv_w[i]; return; }
  i -= 786432;
  if (i < 262144) { owb[i] = (__bf16)out_w[i]; return; }
  i -= 262144;
  if (i < 65536) {
    int hh = i >> 12, qc = i & 4095, qq = qc >> 6, c = qc & 63;
    __bf16 val;
    if (c >= 49)      val = (__bf16)(-30000.0f);
    else if (qq >= 49) val = (__bf16)(0.0f);
    else {
      int dh = qq / 7 - c / 7 + 6;
      int dw = qq % 7 - c % 7 + 6;
      val = (__bf16)rpt[(dh * 13 + dw) * 16 + hh];
    }
    biasb[i] = val;
  }
}

// ---------------------------------------------------------------------------
// cast hidden_states f32 -> bf16 (8 elems/thread)
// ---------------------------------------------------------------------------
__global__ void cast_k(const float* __restrict__ in, __bf16* __restrict__ outb, int n8)
{
  int i = blockIdx.x * blockDim.x + threadIdx.x;
  int stride = gridDim.x * blockDim.x;
  for (; i < n8; i += stride) {
    const float4* p = (const float4*)in + (size_t)i * 2;
    float4 x = p[0], y = p[1];
    bf16x8 o;
    o[0] = (__bf16)x.x; o[1] = (__bf16)x.y; o[2] = (__bf16)x.z; o[3] = (__bf16)x.w;
    o[4] = (__bf16)y.x; o[5] = (__bf16)y.y; o[6] = (__bf16)y.z; o[7] = (__bf16)y.w;
    ((bf16x8*)outb)[i] = o;
  }
}

// ---------------------------------------------------------------------------
// 8-phase 256x256 GEMM (round-5 verbatim, best measured: 220us GEMM1).
// ---------------------------------------------------------------------------
template<int EPI>
__global__ __launch_bounds__(512, 2)
void gemm8p(const __bf16* __restrict__ A, const __bf16* __restrict__ Bt,
            const float* __restrict__ bvec, float* __restrict__ outp,
            __bf16* __restrict__ qb, __bf16* __restrict__ kb, __bf16* __restrict__ vb,
            int N, int K)
{
  __shared__ __align__(16) char lds[131072];
  const int tid = threadIdx.x;
  const int wave = tid >> 6, lane = tid & 63;
  const int g = lane >> 4, r = lane & 15;
  const int l8 = lane >> 3, l7 = lane & 7;
  const int wr = wave >> 2, wc = wave & 3;

  const int ntiles = N >> 8;
  const int nper = gridDim.x >> 3;
  const int b2 = (blockIdx.x & 7) * nper + (blockIdx.x >> 3);
  const int m0 = (b2 / ntiles) << 8;
  const int n0 = (b2 % ntiles) << 8;

  const __bf16* Ag = A + (size_t)(m0 + wave * 8 + l8) * K + (l7 ^ l8) * 8;
  const __bf16* Bg = Bt + (size_t)(n0 + wave * 8 + l8) * K + (l7 ^ l8) * 8;
  const size_t c64 = (size_t)64 * K;

  const int ch0 = (g ^ (r & 7)) << 4;
  const int ch1 = ((4 + g) ^ (r & 7)) << 4;
  const char* Ar = lds + ((wave >> 2) * 128 + r) * 128;
  const char* Br = lds + 32768 + ((wave & 3) * 64 + r) * 128;

  f32x4 acc[8][4] = {};
  bf16x8 a[4][2], b[4][2];

#pragma unroll
  for (int c = 0; c < 4; ++c) {
    gload_lds16(Ag + c * c64, lds + wave * 1024 + c * 8192);
    gload_lds16(Bg + c * c64, lds + 32768 + wave * 1024 + c * 8192);
  }
#pragma unroll
  for (int c = 0; c < 4; ++c) {
    gload_lds16(Ag + 64 + c * c64, lds + 65536 + wave * 1024 + c * 8192);
    gload_lds16(Bg + 64 + c * c64, lds + 65536 + 32768 + wave * 1024 + c * 8192);
  }

#pragma unroll 1
  for (int kt = 0; kt < 8; ++kt) {
    const int cur = (kt & 1) << 16;
    const char* Ab = Ar + cur;
    const char* Bb = Br + cur;
    if (kt == 7) asm volatile("s_waitcnt vmcnt(0)" ::: "memory");
    else         asm volatile("s_waitcnt vmcnt(8)" ::: "memory");
    __builtin_amdgcn_s_barrier();

#pragma unroll
    for (int mi = 0; mi < 4; ++mi) {
      a[mi][0] = *(const bf16x8*)(Ab + mi * 2048 + ch0);
      a[mi][1] = *(const bf16x8*)(Ab + mi * 2048 + ch1);
    }
#pragma unroll
    for (int ni = 0; ni < 2; ++ni) {
      b[ni][0] = *(const bf16x8*)(Bb + ni * 2048 + ch0);
      b[ni][1] = *(const bf16x8*)(Bb + ni * 2048 + ch1);
    }
    __builtin_amdgcn_s_barrier();
    asm volatile("s_waitcnt lgkmcnt(0)" ::: "memory");
    __builtin_amdgcn_s_setprio(1);
#pragma unroll
    for (int mi = 0; mi < 4; ++mi)
#pragma unroll
      for (int ni = 0; ni < 2; ++ni) {
        acc[mi][ni] = MFMA16(a[mi][0], b[ni][0], acc[mi][ni]);
        acc[mi][ni] = MFMA16(a[mi][1], b[ni][1], acc[mi][ni]);
      }
    __builtin_amdgcn_s_setprio(0);
    __builtin_amdgcn_s_barrier();

#pragma unroll
    for (int ni = 2; ni < 4; ++ni) {
      b[ni][0] = *(const bf16x8*)(Bb + ni * 2048 + ch0);
      b[ni][1] = *(const bf16x8*)(Bb + ni * 2048 + ch1);
    }
    __builtin_amdgcn_s_barrier();
    asm volatile("s_waitcnt lgkmcnt(0)" ::: "memory");
    __builtin_amdgcn_s_setprio(1);
#pragma unroll
    for (int mi = 0; mi < 4; ++mi)
#pragma unroll
      for (int ni = 2; ni < 4; ++ni) {
        acc[mi][ni] = MFMA16(a[mi][0], b[ni][0], acc[mi][ni]);
        acc[mi][ni] = MFMA16(a[mi][1], b[ni][1], acc[mi][ni]);
      }
    __builtin_amdgcn_s_setprio(0);
    __builtin_amdgcn_s_barrier();

#pragma unroll
    for (int mi = 0; mi < 4; ++mi) {
      a[mi][0] = *(const bf16x8*)(Ab + (4 + mi) * 2048 + ch0);
      a[mi][1] = *(const bf16x8*)(Ab + (4 + mi) * 2048 + ch1);
    }
    __builtin_amdgcn_s_barrier();
    asm volatile("s_waitcnt lgkmcnt(0)" ::: "memory");
    __builtin_amdgcn_s_setprio(1);
#pragma unroll
    for (int mi = 0; mi < 4; ++mi)
#pragma unroll
      for (int ni = 2; ni < 4; ++ni) {
        acc[4 + mi][ni] = MFMA16(a[mi][0], b[ni][0], acc[4 + mi][ni]);
        acc[4 + mi][ni] = MFMA16(a[mi][1], b[ni][1], acc[4 + mi][ni]);
      }
    __builtin_amdgcn_s_setprio(0);
    __builtin_amdgcn_s_barrier();

    if (kt < 6) {
      const __bf16* Agk = Ag + (kt + 2) * 64;
      const __bf16* Bgk = Bg + (kt + 2) * 64;
      char* Al = lds + cur + wave * 1024;
      char* Bl = lds + cur + 32768 + wave * 1024;
#pragma unroll
      for (int c = 0; c < 4; ++c) {
        gload_lds16(Agk + c * c64, Al + c * 8192);
        gload_lds16(Bgk + c * c64, Bl + c * 8192);
      }
    }
    __builtin_amdgcn_s_setprio(1);
#pragma unroll
    for (int mi = 0; mi < 4; ++mi)
#pragma unroll
      for (int ni = 0; ni < 2; ++ni) {
        acc[4 + mi][ni] = MFMA16(a[mi][0], b[ni][0], acc[4 + mi][ni]);
        acc[4 + mi][ni] = MFMA16(a[mi][1], b[ni][1], acc[4 + mi][ni]);
      }
    __builtin_amdgcn_s_setprio(0);
    __builtin_amdgcn_s_barrier();
  }

  if (EPI == 1) {
#pragma unroll
    for (int mi = 0; mi < 8; ++mi) {
      int row = m0 + (wave >> 2) * 128 + mi * 16 + g * 4;
#pragma unroll
      for (int ni = 0; ni < 4; ++ni) {
        int col = n0 + (wave & 3) * 64 + ni * 16 + r;
        float bv = bvec[col];
#pragma unroll
        for (int j = 0; j < 4; ++j)
          outp[(size_t)(row + j) * N + col] = acc[mi][ni][j] + bv;
      }
    }
  } else {
    __bf16* dst; float scl;
    const int which = n0 >> 9;
    if (which == 0)      { dst = qb; scl = 0.17677669529663687f; }
    else if (which == 1) { dst = kb; scl = 1.0f; }
    else                 { dst = vb; scl = 1.0f; }
    float bv[4];
#pragma unroll
    for (int ni = 0; ni < 4; ++ni) bv[ni] = bvec[n0 + (wave & 3) * 64 + ni * 16 + r];
#pragma unroll
    for (int mi = 0; mi < 8; ++mi) {
#pragma unroll
      for (int j = 0; j < 4; ++j) {
        int m = m0 + (wave >> 2) * 128 + mi * 16 + g * 4 + j;
        int bb = m / 49, t = m - bb * 49;
        __bf16* drow = dst + ((size_t)bb * 16) * 1568 + t * 32;
#pragma unroll
        for (int ni = 0; ni < 4; ++ni) {
          int nl = (n0 + (wave & 3) * 64 + ni * 16 + r) & 511;
          int hh = nl >> 5, d = nl & 31;
          float val = (acc[mi][ni][j] + bv[ni]) * scl;
          drow[(size_t)hh * 1568 + d] = (__bf16)val;
        }
      }
    }
  }
}

// ---------------------------------------------------------------------------
// Attention v3: ONE block per b (grid 2048), 4 waves x 4 sequential heads.
// Mask staged once per b; Vt zeroed once (pads stay 0, P=0 kills stale V);
// per-head pipeline: V loads issued at iter start (hidden under QK+softmax
// of current head via V-scatter-at-iter-end), Q/K for next head issued right
// after current QK^T (their source regs die there). Wave-private LDS, one
// __syncthreads total. Math/layouts identical to the round-2-verified kernel.
// ---------------------------------------------------------------------------
__global__ __launch_bounds__(256, 4)
void attn_k(const __bf16* __restrict__ qb, const __bf16* __restrict__ kb,
            const __bf16* __restrict__ vb, const __bf16* __restrict__ bias_p,
            const float* __restrict__ mask, __bf16* __restrict__ ao)
{
  __shared__ float maskl[64 * 64];
  __shared__ __bf16 Vt[4][32 * 64];
  __shared__ __bf16 Pl[4][16 * 64];
  const int tid = threadIdx.x, wave = tid >> 6, lane = tid & 63;
  const int g = lane >> 4, r = lane & 15;
  const int b = blockIdx.x;
  const bf16x8 z8 = {};
  const f32x4 z4 = {};
  const size_t bbase = (size_t)b * 16;

  // zero own Vt once (pad slots t>=49 stay 0 for all 4 heads)
  bf16x8* vtz = (bf16x8*)Vt[wave];
#pragma unroll
  for (int i = 0; i < 4; ++i) vtz[i * 64 + lane] = z8;

  // V(first head) + Q/K(first head) loads — latency hidden under mask stage
  bf16x8 vv[4];
  int vt_[4], vd0_[4];
  {
    const __bf16* v = vb + (bbase + wave) * 1568;
#pragma unroll
    for (int i = 0; i < 4; ++i) {
      int idx = i * 64 + lane;
      vt_[i] = idx >> 2; vd0_[i] = (idx & 3) << 3;
      vv[i] = (vt_[i] < 49) ? *(const bf16x8*)(v + vt_[i] * 32 + vd0_[i]) : z8;
    }
  }
  bf16x8 qf[4], kf[4];
  {
    const __bf16* q = qb + (bbase + wave) * 1568;
    const __bf16* k = kb + (bbase + wave) * 1568;
#pragma unroll
    for (int i = 0; i < 4; ++i) {
      int row = i * 16 + r;
      qf[i] = (row < 49) ? *(const bf16x8*)(q + row * 32 + g * 8) : z8;
      kf[i] = (row < 49) ? *(const bf16x8*)(k + row * 32 + g * 8) : z8;
    }
  }

  // cooperative mask stage (pad 0, XOR-swizzled f32 columns)
  const float* mb = mask + (size_t)b * 2401;
#pragma unroll
  for (int i = 0; i < 16; ++i) {
    int idx = i * 256 + tid;
    int qq = idx >> 6, c = idx & 63;
    float mv = (qq < 49 && c < 49) ? mb[qq * 49 + c] : 0.0f;
    maskl[qq * 64 + (c ^ ((qq & 7) << 2))] = mv;
  }
  __syncthreads();   // mask + Vt zeros visible

  char* vt = (char*)Vt[wave];
  char* pw = (char*)Pl[wave];
  const int swz = (r & 7) << 4;
  const int mswz = (r & 7) << 2;

  // scatter V(first head) into own Vt
#pragma unroll
  for (int i = 0; i < 4; ++i) {
    if (vt_[i] < 49) {
#pragma unroll
      for (int j = 0; j < 8; ++j) {
        int d = vd0_[i] + j;
        *(__bf16*)(vt + d * 128 + ((vt_[i] * 2) ^ ((d & 7) << 4))) = vv[i][j];
      }
    }
  }

#pragma unroll
  for (int hi = 0; hi < 4; ++hi) {
    const int h = wave + hi * 4;
    __bf16* aob = ao + (size_t)b * 25088 + h * 32;
    const __bf16* bp = bias_p + h * 4096;

    // V fragments for THIS head (scattered at end of previous iter)
    bf16x8 vf[2][2];
#pragma unroll
    for (int di = 0; di < 2; ++di) {
      int row = di * 16 + r;
#pragma unroll
      for (int t = 0; t < 2; ++t)
        vf[di][t] = *(const bf16x8*)(vt + row * 128 + (((t * 32 + g * 8) * 2) ^ ((row & 7) << 4)));
    }

    // issue NEXT head's V loads (drain at iter end)
    bf16x8 vn[4];
    if (hi < 3) {
      const __bf16* v = vb + (bbase + h + 4) * 1568;
#pragma unroll
      for (int i = 0; i < 4; ++i)
        vn[i] = (vt_[i] < 49) ? *(const bf16x8*)(v + vt_[i] * 32 + vd0_[i]) : z8;
    }

    // QK^T for all 4 q-blocks (lane holds S^T fragments)
    f32x4 s01[4], s23[4];   // qi=...: computed per qi below to bound regs
    // -> process per-qi as in the verified kernel
    // issue NEXT head's Q/K right after the last QK MFMA of this head;
    // structure: compute all qi sequentially, prefetch after qi==0's MFMAs.
    bf16x8 qn[4], kn[4];

#pragma unroll
    for (int qi = 0; qi < 4; ++qi) {
      f32x4 s[4];
#pragma unroll
      for (int mi = 0; mi < 4; ++mi) s[mi] = MFMA16(kf[mi], qf[qi], z4);

      if (qi == 3 && hi < 3) {   // qf/kf dead after this point
        const __bf16* q = qb + (bbase + h + 4) * 1568;
        const __bf16* k = kb + (bbase + h + 4) * 1568;
#pragma unroll
        for (int i = 0; i < 4; ++i) {
          int row = i * 16 + r;
          qn[i] = (row < 49) ? *(const bf16x8*)(q + row * 32 + g * 8) : z8;
          kn[i] = (row < 49) ? *(const bf16x8*)(k + row * 32 + g * 8) : z8;
        }
      }

      const int qrow = qi * 16 + r;
#pragma unroll
      for (int mi = 0; mi < 4; ++mi) {
        int c0 = mi * 16 + g * 4;
        bf16x4 b4 = *(const bf16x4*)(bp + qrow * 64 + c0);
        f32x4 m4 = *(const f32x4*)(maskl + qrow * 64 + (c0 ^ mswz));
#pragma unroll
        for (int jj = 0; jj < 4; ++jj)
          s[mi][jj] += (float)b4[jj] + m4[jj];
      }
      f32x4 aa = max4(max4(s[0], s[1]), max4(s[2], s[3]));
      float mx = fmaxf(fmaxf(aa[0], aa[1]), fmaxf(aa[2], aa[3]));
      mx = fmaxf(mx, __shfl_xor(mx, 16));
      mx = fmaxf(mx, __shfl_xor(mx, 32));
      float sum = 0.0f;
#pragma unroll
      for (int mi = 0; mi < 4; ++mi) {
#pragma unroll
        for (int jj = 0; jj < 4; ++jj) {
          float e = __expf(s[mi][jj] - mx);
          s[mi][jj] = e;
          sum += e;
        }
      }
      sum += __shfl_xor(sum, 16);
      sum += __shfl_xor(sum, 32);
      const float rinv = 1.0f / sum;

#pragma unroll
      for (int mi = 0; mi < 4; ++mi) {
        bf16x4 w;
#pragma unroll
        for (int jj = 0; jj < 4; ++jj) w[jj] = (__bf16)(s[mi][jj] * rinv);
        *(bf16x4*)(pw + r * 128 + (((mi * 16 + g * 4) * 2) ^ swz)) = w;
      }
      bf16x8 pa0 = *(const bf16x8*)(pw + r * 128 + ((g * 16) ^ swz));
      bf16x8 pa1 = *(const bf16x8*)(pw + r * 128 + ((64 + g * 16) ^ swz));

#pragma unroll
      for (int di = 0; di < 2; ++di) {
        f32x4 o = MFMA16(pa0, vf[di][0], z4);
        o = MFMA16(pa1, vf[di][1], o);
#pragma unroll
        for (int jj = 0; jj < 4; ++jj) {
          int qq = qi * 16 + g * 4 + jj;
          if (qq < 49)
            aob[(size_t)qq * 512 + di * 16 + r] = (__bf16)o[jj];
        }
      }
    }

    // rotate prefetched head into place; scatter next V (after PV reads done)
    if (hi < 3) {
#pragma unroll
      for (int i = 0; i < 4; ++i) { qf[i] = qn[i]; kf[i] = kn[i]; }
#pragma unroll
      for (int i = 0; i < 4; ++i) {
        if (vt_[i] < 49) {
#pragma unroll
          for (int j = 0; j < 8; ++j) {
            int d = vd0_[i] + j;
            *(__bf16*)(vt + d * 128 + ((vt_[i] * 2) ^ ((d & 7) << 4))) = vn[i][j];
          }
        }
      }
    }
  }
}

// ---------------------------------------------------------------------------
extern "C" void kernel_launch(void* const* d_in, const int* in_sizes, int n_in,
                              void* d_out, int out_size, void* d_ws, size_t ws_size,
                              hipStream_t stream)
{
  const float* hs    = (const float*)d_in[0];
  const float* mask  = (const float*)d_in[1];
  const float* qkv_w = (const float*)d_in[2];
  const float* qkv_b = (const float*)d_in[3];
  const float* out_w = (const float*)d_in[4];
  const float* out_b = (const float*)d_in[5];
  const float* rpt   = (const float*)d_in[6];
  float* out = (float*)d_out;

  char* ws = (char*)d_ws;
  __bf16* hsb  = (__bf16*)(ws);                  // reused as attn-out after GEMM1
  __bf16* qb   = (__bf16*)(ws + 102760448);
  __bf16* kb   = (__bf16*)(ws + 205520896);
  __bf16* vb   = (__bf16*)(ws + 308281344);
  __bf16* qwb  = (__bf16*)(ws + 411041792);
  __bf16* owb  = (__bf16*)(ws + 412614656);
  __bf16* biasb= (__bf16*)(ws + 413138944);      // [16][64][64] bf16

  prep_k<<<4352, 256, 0, stream>>>(qkv_w, out_w, rpt, qwb, owb, biasb);
  cast_k<<<2048, 256, 0, stream>>>(hs, hsb, 6422528);
  gemm8p<0><<<2352, 512, 0, stream>>>(hsb, qwb, qkv_b, nullptr, qb, kb, vb,
                                      1536, 512);
  attn_k<<<2048, 256, 0, stream>>>(qb, kb, vb, biasb, mask, hsb);
  gemm8p<1><<<784, 512, 0, stream>>>(hsb, owb, out_b, out, nullptr, nullptr, nullptr,
                                     512, 512);
}

// Round 11
// 540.200 us; speedup vs baseline: 2.1116x; 1.2009x over previous
//
#include <hip/hip_runtime.h>
#include <hip/hip_bf16.h>

typedef __attribute__((ext_vector_type(8))) __bf16 bf16x8;
typedef __attribute__((ext_vector_type(4))) __bf16 bf16x4;
typedef __attribute__((ext_vector_type(4))) float f32x4;

#define MFMA16(a,b,c) __builtin_amdgcn_mfma_f32_16x16x32_bf16(a,b,c,0,0,0)

__device__ __forceinline__ void gload_lds16(const void* g, void* l) {
  __builtin_amdgcn_global_load_lds(
      (const __attribute__((address_space(1))) void*)g,
      (__attribute__((address_space(3))) void*)l, 16, 0, 0);
}

__device__ __forceinline__ f32x4 max4(f32x4 a, f32x4 b) {
  f32x4 c;
  c[0] = fmaxf(a[0], b[0]); c[1] = fmaxf(a[1], b[1]);
  c[2] = fmaxf(a[2], b[2]); c[3] = fmaxf(a[3], b[3]);
  return c;
}

// ---------------------------------------------------------------------------
// prep: cast weights to bf16, build padded bf16 bias table [16][64][64]
// ---------------------------------------------------------------------------
__global__ void prep_k(const float* __restrict__ qkv_w, const float* __restrict__ out_w,
                       const float* __restrict__ rpt,
                       __bf16* __restrict__ qwb, __bf16* __restrict__ owb,
                       __bf16* __restrict__ biasb)
{
  int i = blockIdx.x * 256 + threadIdx.x;
  if (i < 786432) { qwb[i] = (__bf16)qkv_w[i]; return; }
  i -= 786432;
  if (i < 262144) { owb[i] = (__bf16)out_w[i]; return; }
  i -= 262144;
  if (i < 65536) {
    int hh = i >> 12, qc = i & 4095, qq = qc >> 6, c = qc & 63;
    __bf16 val;
    if (c >= 49)      val = (__bf16)(-30000.0f);
    else if (qq >= 49) val = (__bf16)(0.0f);
    else {
      int dh = qq / 7 - c / 7 + 6;
      int dw = qq % 7 - c % 7 + 6;
      val = (__bf16)rpt[(dh * 13 + dw) * 16 + hh];
    }
    biasb[i] = val;
  }
}

// ---------------------------------------------------------------------------
// cast hidden_states f32 -> bf16 (8 elems/thread)
// ---------------------------------------------------------------------------
__global__ void cast_k(const float* __restrict__ in, __bf16* __restrict__ outb, int n8)
{
  int i = blockIdx.x * blockDim.x + threadIdx.x;
  int stride = gridDim.x * blockDim.x;
  for (; i < n8; i += stride) {
    const float4* p = (const float4*)in + (size_t)i * 2;
    float4 x = p[0], y = p[1];
    bf16x8 o;
    o[0] = (__bf16)x.x; o[1] = (__bf16)x.y; o[2] = (__bf16)x.z; o[3] = (__bf16)x.w;
    o[4] = (__bf16)y.x; o[5] = (__bf16)y.y; o[6] = (__bf16)y.z; o[7] = (__bf16)y.w;
    ((bf16x8*)outb)[i] = o;
  }
}

// ---------------------------------------------------------------------------
// 8-phase 256x256 GEMM (round-5 verbatim, best measured: 220us GEMM1).
// ---------------------------------------------------------------------------
template<int EPI>
__global__ __launch_bounds__(512, 2)
void gemm8p(const __bf16* __restrict__ A, const __bf16* __restrict__ Bt,
            const float* __restrict__ bvec, float* __restrict__ outp,
            __bf16* __restrict__ qb, __bf16* __restrict__ kb, __bf16* __restrict__ vb,
            int N, int K)
{
  __shared__ __align__(16) char lds[131072];
  const int tid = threadIdx.x;
  const int wave = tid >> 6, lane = tid & 63;
  const int g = lane >> 4, r = lane & 15;
  const int l8 = lane >> 3, l7 = lane & 7;

  const int ntiles = N >> 8;
  const int nper = gridDim.x >> 3;
  const int b2 = (blockIdx.x & 7) * nper + (blockIdx.x >> 3);
  const int m0 = (b2 / ntiles) << 8;
  const int n0 = (b2 % ntiles) << 8;

  const __bf16* Ag = A + (size_t)(m0 + wave * 8 + l8) * K + (l7 ^ l8) * 8;
  const __bf16* Bg = Bt + (size_t)(n0 + wave * 8 + l8) * K + (l7 ^ l8) * 8;
  const size_t c64 = (size_t)64 * K;

  const int ch0 = (g ^ (r & 7)) << 4;
  const int ch1 = ((4 + g) ^ (r & 7)) << 4;
  const char* Ar = lds + ((wave >> 2) * 128 + r) * 128;
  const char* Br = lds + 32768 + ((wave & 3) * 64 + r) * 128;

  f32x4 acc[8][4] = {};
  bf16x8 a[4][2], b[4][2];

#pragma unroll
  for (int c = 0; c < 4; ++c) {
    gload_lds16(Ag + c * c64, lds + wave * 1024 + c * 8192);
    gload_lds16(Bg + c * c64, lds + 32768 + wave * 1024 + c * 8192);
  }
#pragma unroll
  for (int c = 0; c < 4; ++c) {
    gload_lds16(Ag + 64 + c * c64, lds + 65536 + wave * 1024 + c * 8192);
    gload_lds16(Bg + 64 + c * c64, lds + 65536 + 32768 + wave * 1024 + c * 8192);
  }

#pragma unroll 1
  for (int kt = 0; kt < 8; ++kt) {
    const int cur = (kt & 1) << 16;
    const char* Ab = Ar + cur;
    const char* Bb = Br + cur;
    if (kt == 7) asm volatile("s_waitcnt vmcnt(0)" ::: "memory");
    else         asm volatile("s_waitcnt vmcnt(8)" ::: "memory");
    __builtin_amdgcn_s_barrier();

#pragma unroll
    for (int mi = 0; mi < 4; ++mi) {
      a[mi][0] = *(const bf16x8*)(Ab + mi * 2048 + ch0);
      a[mi][1] = *(const bf16x8*)(Ab + mi * 2048 + ch1);
    }
#pragma unroll
    for (int ni = 0; ni < 2; ++ni) {
      b[ni][0] = *(const bf16x8*)(Bb + ni * 2048 + ch0);
      b[ni][1] = *(const bf16x8*)(Bb + ni * 2048 + ch1);
    }
    __builtin_amdgcn_s_barrier();
    asm volatile("s_waitcnt lgkmcnt(0)" ::: "memory");
    __builtin_amdgcn_s_setprio(1);
#pragma unroll
    for (int mi = 0; mi < 4; ++mi)
#pragma unroll
      for (int ni = 0; ni < 2; ++ni) {
        acc[mi][ni] = MFMA16(a[mi][0], b[ni][0], acc[mi][ni]);
        acc[mi][ni] = MFMA16(a[mi][1], b[ni][1], acc[mi][ni]);
      }
    __builtin_amdgcn_s_setprio(0);
    __builtin_amdgcn_s_barrier();

#pragma unroll
    for (int ni = 2; ni < 4; ++ni) {
      b[ni][0] = *(const bf16x8*)(Bb + ni * 2048 + ch0);
      b[ni][1] = *(const bf16x8*)(Bb + ni * 2048 + ch1);
    }
    __builtin_amdgcn_s_barrier();
    asm volatile("s_waitcnt lgkmcnt(0)" ::: "memory");
    __builtin_amdgcn_s_setprio(1);
#pragma unroll
    for (int mi = 0; mi < 4; ++mi)
#pragma unroll
      for (int ni = 2; ni < 4; ++ni) {
        acc[mi][ni] = MFMA16(a[mi][0], b[ni][0], acc[mi][ni]);
        acc[mi][ni] = MFMA16(a[mi][1], b[ni][1], acc[mi][ni]);
      }
    __builtin_amdgcn_s_setprio(0);
    __builtin_amdgcn_s_barrier();

#pragma unroll
    for (int mi = 0; mi < 4; ++mi) {
      a[mi][0] = *(const bf16x8*)(Ab + (4 + mi) * 2048 + ch0);
      a[mi][1] = *(const bf16x8*)(Ab + (4 + mi) * 2048 + ch1);
    }
    __builtin_amdgcn_s_barrier();
    asm volatile("s_waitcnt lgkmcnt(0)" ::: "memory");
    __builtin_amdgcn_s_setprio(1);
#pragma unroll
    for (int mi = 0; mi < 4; ++mi)
#pragma unroll
      for (int ni = 2; ni < 4; ++ni) {
        acc[4 + mi][ni] = MFMA16(a[mi][0], b[ni][0], acc[4 + mi][ni]);
        acc[4 + mi][ni] = MFMA16(a[mi][1], b[ni][1], acc[4 + mi][ni]);
      }
    __builtin_amdgcn_s_setprio(0);
    __builtin_amdgcn_s_barrier();

    if (kt < 6) {
      const __bf16* Agk = Ag + (kt + 2) * 64;
      const __bf16* Bgk = Bg + (kt + 2) * 64;
      char* Al = lds + cur + wave * 1024;
      char* Bl = lds + cur + 32768 + wave * 1024;
#pragma unroll
      for (int c = 0; c < 4; ++c) {
        gload_lds16(Agk + c * c64, Al + c * 8192);
        gload_lds16(Bgk + c * c64, Bl + c * 8192);
      }
    }
    __builtin_amdgcn_s_setprio(1);
#pragma unroll
    for (int mi = 0; mi < 4; ++mi)
#pragma unroll
      for (int ni = 0; ni < 2; ++ni) {
        acc[4 + mi][ni] = MFMA16(a[mi][0], b[ni][0], acc[4 + mi][ni]);
        acc[4 + mi][ni] = MFMA16(a[mi][1], b[ni][1], acc[4 + mi][ni]);
      }
    __builtin_amdgcn_s_setprio(0);
    __builtin_amdgcn_s_barrier();
  }

  if (EPI == 1) {
#pragma unroll
    for (int mi = 0; mi < 8; ++mi) {
      int row = m0 + (wave >> 2) * 128 + mi * 16 + g * 4;
#pragma unroll
      for (int ni = 0; ni < 4; ++ni) {
        int col = n0 + (wave & 3) * 64 + ni * 16 + r;
        float bv = bvec[col];
#pragma unroll
        for (int j = 0; j < 4; ++j)
          outp[(size_t)(row + j) * N + col] = acc[mi][ni][j] + bv;
      }
    }
  } else {
    __bf16* dst; float scl;
    const int which = n0 >> 9;
    if (which == 0)      { dst = qb; scl = 0.17677669529663687f; }
    else if (which == 1) { dst = kb; scl = 1.0f; }
    else                 { dst = vb; scl = 1.0f; }
    float bv[4];
#pragma unroll
    for (int ni = 0; ni < 4; ++ni) bv[ni] = bvec[n0 + (wave & 3) * 64 + ni * 16 + r];
#pragma unroll
    for (int mi = 0; mi < 8; ++mi) {
#pragma unroll
      for (int j = 0; j < 4; ++j) {
        int m = m0 + (wave >> 2) * 128 + mi * 16 + g * 4 + j;
        int bb = m / 49, t = m - bb * 49;
        __bf16* drow = dst + ((size_t)bb * 16) * 1568 + t * 32;
#pragma unroll
        for (int ni = 0; ni < 4; ++ni) {
          int nl = (n0 + (wave & 3) * 64 + ni * 16 + r) & 511;
          int hh = nl >> 5, d = nl & 31;
          float val = (acc[mi][ni][j] + bv[ni]) * scl;
          drow[(size_t)hh * 1568 + d] = (__bf16)val;
        }
      }
    }
  }
}

// ---------------------------------------------------------------------------
// Attention (round-2 verified structure + bias-in-registers prefetch):
// 4 waves/block = 4 heads of one b. Swapped QK^T; vector bias (prefetched to
// 32 VGPRs at block start, drains under mask stage -> removes 4 L2-latency
// exposures per qi from the serial chain) and mask (float4, swizzled LDS).
// ---------------------------------------------------------------------------
__global__ __launch_bounds__(256, 4)
void attn_k(const __bf16* __restrict__ qb, const __bf16* __restrict__ kb,
            const __bf16* __restrict__ vb, const __bf16* __restrict__ bias_p,
            const float* __restrict__ mask, __bf16* __restrict__ ao)
{
  __shared__ float maskl[64 * 64];
  __shared__ __bf16 Vt[4][32 * 64];
  __shared__ __bf16 Pl[4][16 * 64];
  const int tid = threadIdx.x, wave = tid >> 6, lane = tid & 63;
  const int g = lane >> 4, r = lane & 15;
  const int b = blockIdx.x >> 2, hg = blockIdx.x & 3;
  const int h = hg * 4 + wave;
  const size_t bh = (size_t)b * 16 + h;
  const __bf16* q = qb + bh * 1568;
  const __bf16* k = kb + bh * 1568;
  const __bf16* v = vb + bh * 1568;
  const bf16x8 z8 = {};
  const f32x4 z4 = {};

  // bias prefetch: 16 x bf16x4 (one per (qi,mi)), issued as one batch
  bf16x4 bfr[4][4];
  {
    const __bf16* bp = bias_p + h * 4096;
#pragma unroll
    for (int qi = 0; qi < 4; ++qi)
#pragma unroll
      for (int mi = 0; mi < 4; ++mi)
        bfr[qi][mi] = *(const bf16x4*)(bp + (qi * 16 + r) * 64 + mi * 16 + g * 4);
  }

  bf16x8* vtz = (bf16x8*)Vt[wave];
#pragma unroll
  for (int i = 0; i < 4; ++i) vtz[i * 64 + lane] = z8;

  const float* mb = mask + (size_t)b * 2401;
#pragma unroll
  for (int i = 0; i < 16; ++i) {
    int idx = i * 256 + tid;
    int qq = idx >> 6, c = idx & 63;
    float mv = (qq < 49 && c < 49) ? mb[qq * 49 + c] : 0.0f;
    maskl[qq * 64 + (c ^ ((qq & 7) << 2))] = mv;
  }

  bf16x8 kf[4], qf[4];
#pragma unroll
  for (int i = 0; i < 4; ++i) {
    int row = i * 16 + r;
    kf[i] = (row < 49) ? *(const bf16x8*)(k + row * 32 + g * 8) : z8;
    qf[i] = (row < 49) ? *(const bf16x8*)(q + row * 32 + g * 8) : z8;
  }

  __syncthreads();

  char* vt = (char*)Vt[wave];
#pragma unroll
  for (int i = 0; i < 4; ++i) {
    int idx = i * 64 + lane;
    int t = idx >> 2, d0 = (idx & 3) << 3;
    if (t < 49) {
      bf16x8 vv = *(const bf16x8*)(v + t * 32 + d0);
#pragma unroll
      for (int j = 0; j < 8; ++j) {
        int d = d0 + j;
        *(__bf16*)(vt + d * 128 + ((t * 2) ^ ((d & 7) << 4))) = vv[j];
      }
    }
  }

  bf16x8 vf[2][2];
#pragma unroll
  for (int di = 0; di < 2; ++di) {
    int row = di * 16 + r;
#pragma unroll
    for (int t = 0; t < 2; ++t)
      vf[di][t] = *(const bf16x8*)(vt + row * 128 + (((t * 32 + g * 8) * 2) ^ ((row & 7) << 4)));
  }

  char* pw = (char*)Pl[wave];
  __bf16* aob = ao + (size_t)b * 25088 + h * 32;
  const int swz = (r & 7) << 4;
  const int mswz = (r & 7) << 2;

#pragma unroll
  for (int qi = 0; qi < 4; ++qi) {
    f32x4 s[4];
#pragma unroll
    for (int mi = 0; mi < 4; ++mi) s[mi] = MFMA16(kf[mi], qf[qi], z4);

    const int qrow = qi * 16 + r;
#pragma unroll
    for (int mi = 0; mi < 4; ++mi) {
      int c0 = mi * 16 + g * 4;
      f32x4 m4 = *(const f32x4*)(maskl + qrow * 64 + (c0 ^ mswz));
#pragma unroll
      for (int jj = 0; jj < 4; ++jj)
        s[mi][jj] += (float)bfr[qi][mi][jj] + m4[jj];
    }
    f32x4 aa = max4(max4(s[0], s[1]), max4(s[2], s[3]));
    float mx = fmaxf(fmaxf(aa[0], aa[1]), fmaxf(aa[2], aa[3]));
    mx = fmaxf(mx, __shfl_xor(mx, 16));
    mx = fmaxf(mx, __shfl_xor(mx, 32));
    float sum = 0.0f;
#pragma unroll
    for (int mi = 0; mi < 4; ++mi) {
#pragma unroll
      for (int jj = 0; jj < 4; ++jj) {
        float e = __expf(s[mi][jj] - mx);
        s[mi][jj] = e;
        sum += e;
      }
    }
    sum += __shfl_xor(sum, 16);
    sum += __shfl_xor(sum, 32);
    const float rinv = 1.0f / sum;

#pragma unroll
    for (int mi = 0; mi < 4; ++mi) {
      bf16x4 w;
#pragma unroll
      for (int jj = 0; jj < 4; ++jj) w[jj] = (__bf16)(s[mi][jj] * rinv);
      *(bf16x4*)(pw + r * 128 + (((mi * 16 + g * 4) * 2) ^ swz)) = w;
    }
    bf16x8 pa0 = *(const bf16x8*)(pw + r * 128 + ((g * 16) ^ swz));
    bf16x8 pa1 = *(const bf16x8*)(pw + r * 128 + ((64 + g * 16) ^ swz));

#pragma unroll
    for (int di = 0; di < 2; ++di) {
      f32x4 o = MFMA16(pa0, vf[di][0], z4);
      o = MFMA16(pa1, vf[di][1], o);
#pragma unroll
      for (int jj = 0; jj < 4; ++jj) {
        int qq = qi * 16 + g * 4 + jj;
        if (qq < 49)
          aob[(size_t)qq * 512 + di * 16 + r] = (__bf16)o[jj];
      }
    }
  }
}

// ---------------------------------------------------------------------------
extern "C" void kernel_launch(void* const* d_in, const int* in_sizes, int n_in,
                              void* d_out, int out_size, void* d_ws, size_t ws_size,
                              hipStream_t stream)
{
  const float* hs    = (const float*)d_in[0];
  const float* mask  = (const float*)d_in[1];
  const float* qkv_w = (const float*)d_in[2];
  const float* qkv_b = (const float*)d_in[3];
  const float* out_w = (const float*)d_in[4];
  const float* out_b = (const float*)d_in[5];
  const float* rpt   = (const float*)d_in[6];
  float* out = (float*)d_out;

  char* ws = (char*)d_ws;
  __bf16* hsb  = (__bf16*)(ws);                  // reused as attn-out after GEMM1
  __bf16* qb   = (__bf16*)(ws + 102760448);
  __bf16* kb   = (__bf16*)(ws + 205520896);
  __bf16* vb   = (__bf16*)(ws + 308281344);
  __bf16* qwb  = (__bf16*)(ws + 411041792);
  __bf16* owb  = (__bf16*)(ws + 412614656);
  __bf16* biasb= (__bf16*)(ws + 413138944);      // [16][64][64] bf16

  prep_k<<<4352, 256, 0, stream>>>(qkv_w, out_w, rpt, qwb, owb, biasb);
  cast_k<<<2048, 256, 0, stream>>>(hs, hsb, 6422528);
  gemm8p<0><<<2352, 512, 0, stream>>>(hsb, qwb, qkv_b, nullptr, qb, kb, vb,
                                      1536, 512);
  attn_k<<<8192, 256, 0, stream>>>(qb, kb, vb, biasb, mask, hsb);
  gemm8p<1><<<784, 512, 0, stream>>>(hsb, owb, out_b, out, nullptr, nullptr, nullptr,
                                     512, 512);
}